// Round 13
// baseline (1167.616 us; speedup 1.0000x reference)
//
#include <hip/hip_runtime.h>
#include <hip/hip_fp16.h>
#include <stdint.h>

#define NROWS 8192
#define DIM 64
#define EPS 0.1f

typedef float f32x4 __attribute__((ext_vector_type(4)));
typedef short s16x8 __attribute__((ext_vector_type(8)));
typedef _Float16 h2 __attribute__((ext_vector_type(2)));

// ---------- helpers ----------

__device__ __forceinline__ float wave_reduce_add(float v) {
  #pragma unroll
  for (int off = 32; off > 0; off >>= 1) v += __shfl_down(v, off, 64);
  return v;
}

// pack two fp32 -> bf16x2 dword by truncation (1 v_perm); x -> low, y -> high.
__device__ __forceinline__ uint32_t pack_bf16_trunc(float x, float y) {
  return __builtin_amdgcn_perm(__float_as_uint(y), __float_as_uint(x), 0x07060302u);
}

// ---------- fp4 e2m1 encode/decode (block-scaled, scale applied manually) ----

#if __has_builtin(__builtin_amdgcn_cvt_scalef32_pk_f16_fp4)
#define CVT4H(kd, sel) __builtin_amdgcn_cvt_scalef32_pk_f16_fp4((kd), 1.0f, (sel))
#else
__device__ __forceinline__ h2 cvt4h_fb(uint32_t kd, int sel) {
  uint32_t byt  = (kd >> (sel * 8)) & 0xFFu;
  uint32_t selv = (byt & 0xFu) | ((byt >> 4) << 16);
  uint32_t tb = __builtin_amdgcn_perm(0x46444240u, 0x3E3C3800u, selv);
  uint32_t d  = ((tb & 0xFFu) << 8) | ((tb & 0xFF0000u) << 8);
  return __builtin_bit_cast(h2, d);
}
#define CVT4H(kd, sel) cvt4h_fb((kd), (sel))
#endif

#if __has_builtin(__builtin_amdgcn_cvt_scalef32_pk_fp4_f32)
__device__ __forceinline__ uint32_t enc4(float q0, float q1, float q2, float q3) {
  uint32_t pk = __builtin_amdgcn_cvt_scalef32_pk_fp4_f32(0u, q0, q1, 1.0f, 0);
  pk = __builtin_amdgcn_cvt_scalef32_pk_fp4_f32(pk, q2, q3, 1.0f, 1);
  return pk & 0xFFFFu;
}
#else
__device__ __forceinline__ uint32_t enc1(float q) {
  float c = fminf(floorf(2.f * q + 0.5f), 4.f);
  c += (q > 2.5f) ? 1.f : 0.f;
  c += (q > 3.5f) ? 1.f : 0.f;
  return (uint32_t)c;
}
__device__ __forceinline__ uint32_t enc4(float q0, float q1, float q2, float q3) {
  return enc1(q0) | (enc1(q1) << 4) | (enc1(q2) << 8) | (enc1(q3) << 12);
}
#endif

#define FP4DOT(kd, xv, acc)                                                          \
  acc = __builtin_amdgcn_fdot2(CVT4H((kd), 0), __builtin_bit_cast(h2, (xv).x), acc, false); \
  acc = __builtin_amdgcn_fdot2(CVT4H((kd), 1), __builtin_bit_cast(h2, (xv).y), acc, false); \
  acc = __builtin_amdgcn_fdot2(CVT4H((kd), 2), __builtin_bit_cast(h2, (xv).z), acc, false); \
  acc = __builtin_amdgcn_fdot2(CVT4H((kd), 3), __builtin_bit_cast(h2, (xv).w), acc, false);

#define FIN1(kd, xd_, sel)                                                           \
  {                                                                                  \
    h2 kvp = CVT4H((kd), sel);                                                       \
    h2 xp  = __builtin_bit_cast(h2, (xd_));                                          \
    s1b = __builtin_amdgcn_fdot2(kvp, xp, s1b, false);                               \
    float v0 = (float)kvp.x, v1 = (float)kvp.y;                                      \
    float x0 = (float)xp.x,  x1 = (float)xp.y;                                       \
    t2b = fmaf(v0 * x0, __logf(fmaxf(v0, 1e-8f)), t2b);                              \
    t2b = fmaf(v1 * x1, __logf(fmaxf(v1, 1e-8f)), t2b);                              \
  }
#define FINDOT(kd, xv) FIN1(kd, (xv).x, 0) FIN1(kd, (xv).y, 1) FIN1(kd, (xv).z, 2) FIN1(kd, (xv).w, 3)

// ---------- small kernels ----------

__global__ __launch_bounds__(256) void rownorm_kernel(
    const float* __restrict__ P, const float* __restrict__ Q,
    float* __restrict__ p2, float* __restrict__ q2,
    float* __restrict__ rowsum) {
  int wid  = threadIdx.x >> 6;
  int lane = threadIdx.x & 63;
  int row  = blockIdx.x * 4 + wid;  // 0..16383
  const float* X;
  float* out;
  int r;
  if (row < NROWS) { X = P; out = p2; r = row; }
  else             { X = Q; out = q2; r = row - NROWS; }
  float v = X[(size_t)r * DIM + lane];
  float s = wave_reduce_add(v * v);
  if (lane == 0) out[r] = s;
  if (row < NROWS && lane == 1) rowsum[r] = 0.f;   // zero for kgen's atomics
}

// vb16[i] = f16(64 / rowsum[i]); also zeroes the barrier words.
__global__ void v1_kernel(const float* __restrict__ rowsum,
                          unsigned short* __restrict__ vb16,
                          unsigned int* __restrict__ barr) {
  int i = blockIdx.x * blockDim.x + threadIdx.x;
  if (i < NROWS) vb16[i] = __half_as_ushort(__float2half(64.0f / rowsum[i]));
  if (i < 512) barr[i] = 0u;
}

// ---------- kgen (r12-proven): MFMA bf16 -> fp4 K + e8m0 scales + row sums ----

struct KgenSmem {
  unsigned char A[128 * 128];
  unsigned char B[128 * 128];
  float p2s[128];
  float q2s[128];
};

__device__ __forceinline__ int swiz_off(int row, int kc) {
  return row * 128 + ((kc ^ (row & 7)) << 4);
}

__global__ __launch_bounds__(256) void kgen_kernel(
    const float* __restrict__ P, const float* __restrict__ Q,
    const float* __restrict__ p2, const float* __restrict__ q2,
    unsigned char* __restrict__ K4, unsigned char* __restrict__ scales,
    float* __restrict__ rowsum) {
  __shared__ KgenSmem sm;
  const int t  = threadIdx.x;
  const int bi = blockIdx.y * 128;
  const int bj = blockIdx.x * 128;

  {
    const float4* P4 = (const float4*)(P + (size_t)bi * DIM);
    const float4* Q4 = (const float4*)(Q + (size_t)bj * DIM);
    #pragma unroll
    for (int it = 0; it < 4; ++it) {
      int idx = t + it * 256;
      int row = idx >> 3;
      int kc  = idx & 7;
      int g   = row * 16 + kc * 2;
      float4 a0 = P4[g], a1 = P4[g + 1];
      float4 b0 = Q4[g], b1 = Q4[g + 1];
      uint4 pa, pb;
      pa.x = pack_bf16_trunc(-2.f * a0.x, -2.f * a0.y);
      pa.y = pack_bf16_trunc(-2.f * a0.z, -2.f * a0.w);
      pa.z = pack_bf16_trunc(-2.f * a1.x, -2.f * a1.y);
      pa.w = pack_bf16_trunc(-2.f * a1.z, -2.f * a1.w);
      pb.x = pack_bf16_trunc(b0.x, b0.y);
      pb.y = pack_bf16_trunc(b0.z, b0.w);
      pb.z = pack_bf16_trunc(b1.x, b1.y);
      pb.w = pack_bf16_trunc(b1.z, b1.w);
      *(uint4*)(sm.A + swiz_off(row, kc)) = pa;
      *(uint4*)(sm.B + swiz_off(row, kc)) = pb;
    }
    if (t < 128)                   sm.p2s[t]       = p2[bi + t];
    else                           sm.q2s[t - 128] = q2[bj + t - 128];
  }
  __syncthreads();

  const int w        = t >> 6;
  const int lane     = t & 63;
  const int quad     = lane >> 4;
  const int m16      = lane & 15;
  const int wave_row = (w >> 1) * 64;
  const int wave_col = (w & 1) * 64;

  float pn[4];
  f32x4 qn[4];
  #pragma unroll
  for (int ti = 0; ti < 4; ++ti) pn[ti] = sm.p2s[wave_row + ti * 16 + m16];
  #pragma unroll
  for (int tj = 0; tj < 4; ++tj)
    qn[tj] = *(const f32x4*)&sm.q2s[wave_col + tj * 16 + quad * 4];

  f32x4 acc[4][4];
  #pragma unroll
  for (int ti = 0; ti < 4; ++ti)
    #pragma unroll
    for (int tj = 0; tj < 4; ++tj) acc[ti][tj] = qn[tj] + pn[ti];

  #pragma unroll
  for (int kstep = 0; kstep < 2; ++kstep) {
    const int kc = kstep * 4 + quad;
    s16x8 af[4], bf[4];
    #pragma unroll
    for (int ti = 0; ti < 4; ++ti)
      af[ti] = *(const s16x8*)(sm.A + swiz_off(wave_row + ti * 16 + m16, kc));
    #pragma unroll
    for (int tj = 0; tj < 4; ++tj)
      bf[tj] = *(const s16x8*)(sm.B + swiz_off(wave_col + tj * 16 + m16, kc));
    #pragma unroll
    for (int ti = 0; ti < 4; ++ti)
      #pragma unroll
      for (int tj = 0; tj < 4; ++tj)
        acc[ti][tj] = __builtin_amdgcn_mfma_f32_16x16x32_bf16(
            bf[tj], af[ti], acc[ti][tj], 0, 0, 0);
  }

  #pragma unroll
  for (int ti = 0; ti < 4; ++ti) {
    const int row = bi + wave_row + ti * 16 + m16;
    float kv[4][4];
    float mlo = 0.f, mhi = 0.f, rs = 0.f;
    #pragma unroll
    for (int tj = 0; tj < 4; ++tj) {
      f32x4 sq = acc[ti][tj];
      kv[tj][0] = __expf(-10.f * __builtin_amdgcn_sqrtf(fmaxf(sq.x, 0.f)));
      kv[tj][1] = __expf(-10.f * __builtin_amdgcn_sqrtf(fmaxf(sq.y, 0.f)));
      kv[tj][2] = __expf(-10.f * __builtin_amdgcn_sqrtf(fmaxf(sq.z, 0.f)));
      kv[tj][3] = __expf(-10.f * __builtin_amdgcn_sqrtf(fmaxf(sq.w, 0.f)));
      float mt = fmaxf(fmaxf(kv[tj][0], kv[tj][1]), fmaxf(kv[tj][2], kv[tj][3]));
      if (tj < 2) mlo = fmaxf(mlo, mt); else mhi = fmaxf(mhi, mt);
      rs += (kv[tj][0] + kv[tj][1]) + (kv[tj][2] + kv[tj][3]);
    }
    mlo = fmaxf(mlo, __shfl_xor(mlo, 16, 64));
    mlo = fmaxf(mlo, __shfl_xor(mlo, 32, 64));
    mhi = fmaxf(mhi, __shfl_xor(mhi, 16, 64));
    mhi = fmaxf(mhi, __shfl_xor(mhi, 32, 64));
    uint32_t eblo = (__float_as_uint(mlo) >> 23) - 1u;
    uint32_t ebhi = (__float_as_uint(mhi) >> 23) - 1u;
    float silo = __uint_as_float((254u - eblo) << 23);
    float sihi = __uint_as_float((254u - ebhi) << 23);
    #pragma unroll
    for (int tj = 0; tj < 4; ++tj) {
      float si = (tj < 2) ? silo : sihi;
      uint32_t pk = enc4(kv[tj][0] * si, kv[tj][1] * si,
                         kv[tj][2] * si, kv[tj][3] * si);
      *(unsigned short*)(K4 + (size_t)row * (NROWS / 2) +
                         ((bj + wave_col + tj * 16 + quad * 4) >> 1)) =
          (unsigned short)pk;
    }
    if (quad == 0) {
      *(unsigned short*)(scales + (size_t)row * 256 + ((bj + wave_col) >> 5)) =
          (unsigned short)((eblo & 0xFFu) | ((ebhi & 0xFFu) << 8));
    }
    float v = rs;
    v += __shfl_xor(v, 16, 64);
    v += __shfl_xor(v, 32, 64);
    if (quad == 0) atomicAdd(&rowsum[row], v);
  }
}

// ---------- sinkfast: K resident in LDS, 9 passes, hand-rolled tree barrier ----
// 1024 blocks x 256 thr, coop launch (co-residency only; NO grid.sync).
// Each block owns 8 rows: K nibbles (32 KB) + scales (2 KB) staged in LDS once.
// Per pass: read x (f16, global), dot from LDS, write y via agent release
// store, tree barrier (32 leaves -> root -> flag), acquire fence.

__global__ __launch_bounds__(256, 4) void sinkfast_kernel(
    const unsigned char* __restrict__ K4, const unsigned char* __restrict__ scales,
    unsigned short* __restrict__ ub16, unsigned short* __restrict__ vb16,
    float* __restrict__ partials, unsigned int* __restrict__ barr,
    float* __restrict__ out) {
  __shared__ uint32_t kls[8 * 1024];   // 32 KB: 8 rows x 4096 B of nibbles
  __shared__ uint32_t sls[8 * 64];     // 2 KB: 8 rows x 256 B of e8m0 scales
  __shared__ float sred[4];
  const int t = threadIdx.x, lane = t & 63, w = t >> 6;
  const int rowbase = blockIdx.x * 8;

  // ---- stage this block's K slice into LDS (once) ----
  {
    const uint4* g4 = (const uint4*)(K4 + (size_t)rowbase * (NROWS / 2));
    uint4* l4 = (uint4*)kls;
    #pragma unroll
    for (int i = 0; i < 8; ++i) l4[t + i * 256] = g4[t + i * 256];
    const uint2* sg = (const uint2*)(scales + (size_t)rowbase * 256);
    ((uint2*)sls)[t] = sg[t];          // 256 uint2 = 2 KB
  }
  __syncthreads();

  #pragma unroll 1
  for (int m = 1; m <= 9; ++m) {
    const unsigned short* xin = (m & 1) ? vb16 : ub16;
    uint32_t* yout32 = (uint32_t*)((m & 1) ? ub16 : vb16);
    const uint4* x4 = (const uint4*)xin;

    if (m < 9) {
      float ss[2];
      #pragma unroll 1
      for (int rr = 0; rr < 2; ++rr) {
        const int lrow = w * 2 + rr;
        float acc = 0.f;
        #pragma unroll
        for (int s = 0; s < 4; ++s) {
          const int b = s * 64 + lane;
          uint4 kq = *(const uint4*)&kls[lrow * 1024 + b * 4];
          float S = __uint_as_float(
              ((sls[lrow * 64 + (b >> 2)] >> ((b & 3) * 8)) & 0xFFu) << 23);
          uint4 xa = x4[b * 4 + 0], xb = x4[b * 4 + 1];
          uint4 xc = x4[b * 4 + 2], xd = x4[b * 4 + 3];
          float d0 = 0.f, d1 = 0.f;
          FP4DOT(kq.x, xa, d0)
          FP4DOT(kq.y, xb, d1)
          FP4DOT(kq.z, xc, d0)
          FP4DOT(kq.w, xd, d1)
          acc = fmaf(S, d0 + d1, acc);
        }
        ss[rr] = wave_reduce_add(acc);
      }
      if (lane == 0) {
        uint32_t pk = __builtin_bit_cast(
            uint32_t, __builtin_amdgcn_cvt_pkrtz(1.0f / ss[0], 1.0f / ss[1]));
        __hip_atomic_store(&yout32[blockIdx.x * 4 + w], pk,
                           __ATOMIC_RELEASE, __HIP_MEMORY_SCOPE_AGENT);
      }
      // ---- barrier m ----
      __syncthreads();   // all waves' y stores retired (vmcnt drained)
      if (t == 0) {
        unsigned old = __hip_atomic_fetch_add(&barr[m * 32 + (blockIdx.x & 31)], 1u,
                                              __ATOMIC_ACQ_REL, __HIP_MEMORY_SCOPE_AGENT);
        if (old == 31u) {
          unsigned r = __hip_atomic_fetch_add(&barr[320 + m], 1u,
                                              __ATOMIC_ACQ_REL, __HIP_MEMORY_SCOPE_AGENT);
          if (r == 31u)
            __hip_atomic_store(&barr[352 + m], 1u,
                               __ATOMIC_RELEASE, __HIP_MEMORY_SCOPE_AGENT);
        }
        int spins = 0;
        while (__hip_atomic_load(&barr[352 + m], __ATOMIC_ACQUIRE,
                                 __HIP_MEMORY_SCOPE_AGENT) == 0u) {
          __builtin_amdgcn_s_sleep(8);
          if (++spins > 200000) break;   // failsafe: no infinite hang
        }
      }
      __syncthreads();
      __builtin_amdgcn_fence(__ATOMIC_ACQUIRE, "agent");  // fresh x next pass
    } else {
      // ---- final pass: fused loss ----
      float wloss = 0.f;
      #pragma unroll 1
      for (int rr = 0; rr < 2; ++rr) {
        const int lrow = w * 2 + rr;
        float s1 = 0.f, s2 = 0.f;
        #pragma unroll
        for (int s = 0; s < 4; ++s) {
          const int b = s * 64 + lane;
          uint4 kq = *(const uint4*)&kls[lrow * 1024 + b * 4];
          uint32_t sb = (sls[lrow * 64 + (b >> 2)] >> ((b & 3) * 8)) & 0xFFu;
          float S = __uint_as_float(sb << 23);
          float lnS = ((float)(int)sb - 127.f) * 0.69314718f;
          uint4 xa = x4[b * 4 + 0], xb = x4[b * 4 + 1];
          uint4 xc = x4[b * 4 + 2], xd = x4[b * 4 + 3];
          float s1b = 0.f, t2b = 0.f;
          FINDOT(kq.x, xa)
          FINDOT(kq.y, xb)
          FINDOT(kq.z, xc)
          FINDOT(kq.w, xd)
          s1 = fmaf(S, s1b, s1);
          s2 = fmaf(S, fmaf(lnS, s1b, t2b), s2);
        }
        s1 = wave_reduce_add(s1);
        s2 = wave_reduce_add(s2);
        if (lane == 0) wloss += (-EPS) * s2 / s1;
      }
      if (lane == 0) sred[w] = wloss;
      __syncthreads();
      if (t == 0) {
        float p = sred[0] + sred[1] + sred[2] + sred[3];
        __hip_atomic_store(&partials[blockIdx.x], p,
                           __ATOMIC_RELEASE, __HIP_MEMORY_SCOPE_AGENT);
        unsigned old = __hip_atomic_fetch_add(&barr[400], 1u,
                                              __ATOMIC_ACQ_REL, __HIP_MEMORY_SCOPE_AGENT);
        if (old == 1023u) {   // last block reduces
          __builtin_amdgcn_fence(__ATOMIC_ACQUIRE, "agent");
          float s = 0.f;
          for (int i = 0; i < 1024; ++i) s += partials[i];
          out[0] = s;
        }
      }
    }
  }
}

// ---------- fallback (non-coop) chain: r12-proven ----------

__global__ __launch_bounds__(256) void matvec_fp4(
    const unsigned char* __restrict__ K4, const unsigned char* __restrict__ scales,
    const unsigned short* __restrict__ xin, unsigned short* __restrict__ yout) {
  const int t = threadIdx.x, lane = t & 63, w = t >> 6;
  const int row = blockIdx.x * 4 + w;
  const uint4* krow = (const uint4*)(K4 + (size_t)row * (NROWS / 2));
  const unsigned char* srow = scales + (size_t)row * 256;
  const uint4* x4 = (const uint4*)xin;
  float total = 0.f;
  #pragma unroll
  for (int s = 0; s < 4; ++s) {
    const int b = s * 64 + lane;
    uint4 kq = krow[b];
    float S = __uint_as_float((uint32_t)srow[b] << 23);
    uint4 xa = x4[b * 4 + 0], xb = x4[b * 4 + 1];
    uint4 xc = x4[b * 4 + 2], xd = x4[b * 4 + 3];
    float a0 = 0.f, a1 = 0.f;
    FP4DOT(kq.x, xa, a0)
    FP4DOT(kq.y, xb, a1)
    FP4DOT(kq.z, xc, a0)
    FP4DOT(kq.w, xd, a1)
    total = fmaf(S, a0 + a1, total);
  }
  float sm = wave_reduce_add(total);
  if (lane == 0) yout[row] = __half_as_ushort(__float2half(1.0f / sm));
}

__global__ __launch_bounds__(256) void final_fp4(
    const unsigned char* __restrict__ K4, const unsigned char* __restrict__ scales,
    const unsigned short* __restrict__ xin, float* __restrict__ partials) {
  const int t = threadIdx.x, lane = t & 63, w = t >> 6;
  const int row = blockIdx.x * 4 + w;
  const uint4* krow = (const uint4*)(K4 + (size_t)row * (NROWS / 2));
  const unsigned char* srow = scales + (size_t)row * 256;
  const uint4* x4 = (const uint4*)xin;
  float s1 = 0.f, s2 = 0.f;
  #pragma unroll
  for (int s = 0; s < 4; ++s) {
    const int b = s * 64 + lane;
    uint4 kq = krow[b];
    uint32_t sb = srow[b];
    float S = __uint_as_float(sb << 23);
    float lnS = ((float)(int)sb - 127.f) * 0.69314718f;
    uint4 xa = x4[b * 4 + 0], xb = x4[b * 4 + 1];
    uint4 xc = x4[b * 4 + 2], xd = x4[b * 4 + 3];
    float s1b = 0.f, t2b = 0.f;
    FINDOT(kq.x, xa)
    FINDOT(kq.y, xb)
    FINDOT(kq.z, xc)
    FINDOT(kq.w, xd)
    s1 = fmaf(S, s1b, s1);
    s2 = fmaf(S, fmaf(lnS, s1b, t2b), s2);
  }
  s1 = wave_reduce_add(s1);
  s2 = wave_reduce_add(s2);
  __shared__ float sred[4];
  if (lane == 0) sred[w] = (-EPS) * s2 / s1;
  __syncthreads();
  if (t == 0) partials[blockIdx.x] = sred[0] + sred[1] + sred[2] + sred[3];
}

__global__ __launch_bounds__(256) void reduce_kernel(
    const float* __restrict__ partials, float* __restrict__ out) {
  const int t = threadIdx.x;
  float s = 0.f;
  #pragma unroll
  for (int i = 0; i < 8; ++i) s += partials[t + i * 256];
  s = wave_reduce_add(s);
  __shared__ float red[4];
  int lane = t & 63, wid = t >> 6;
  if (lane == 0) red[wid] = s;
  __syncthreads();
  if (t == 0) out[0] = red[0] + red[1] + red[2] + red[3];
}

// ---------- launch ----------

extern "C" void kernel_launch(void* const* d_in, const int* in_sizes, int n_in,
                              void* d_out, int out_size, void* d_ws, size_t ws_size,
                              hipStream_t stream) {
  const float* P = (const float*)d_in[0];
  const float* Q = (const float*)d_in[1];
  float* out = (float*)d_out;

  char* ws = (char*)d_ws;
  unsigned char* K4     = (unsigned char*)ws;                    // 33554432 B
  unsigned char* scales = (unsigned char*)(ws + 33554432);       // 2097152 B
  float* p2       = (float*)(ws + 35651584);
  float* q2       = p2 + NROWS;
  float* rowsum   = q2 + NROWS;
  float* partials = rowsum + NROWS;                              // 2048 slots
  unsigned int* barr = (unsigned int*)(partials + NROWS);        // 512 u32
  unsigned short* ub16 = (unsigned short*)(barr + 512);
  unsigned short* vb16 = ub16 + NROWS;

  rownorm_kernel<<<(2 * NROWS) / 4, 256, 0, stream>>>(P, Q, p2, q2, rowsum);
  kgen_kernel<<<dim3(NROWS / 128, NROWS / 128), 256, 0, stream>>>(
      P, Q, p2, q2, K4, scales, rowsum);
  v1_kernel<<<NROWS / 256, 256, 0, stream>>>(rowsum, vb16, barr);

  void* args[7] = {(void*)&K4, (void*)&scales, (void*)&ub16, (void*)&vb16,
                   (void*)&partials, (void*)&barr, (void*)&out};
  hipError_t err = hipLaunchCooperativeKernel((const void*)sinkfast_kernel,
                                              dim3(1024), dim3(256), args, 0, stream);
  if (err != hipSuccess) {
    // fallback: r12 chain
    for (int m = 1; m < 9; ++m) {
      const unsigned short* xin = (m & 1) ? vb16 : ub16;
      unsigned short* yout      = (m & 1) ? ub16 : vb16;
      matvec_fp4<<<NROWS / 4, 256, 0, stream>>>(K4, scales, xin, yout);
    }
    final_fp4<<<NROWS / 4, 256, 0, stream>>>(K4, scales, vb16, partials);
    reduce_kernel<<<1, 256, 0, stream>>>(partials, out);
  }
}

// Round 14
// 232.044 us; speedup vs baseline: 5.0319x; 5.0319x over previous
//
#include <hip/hip_runtime.h>
#include <hip/hip_fp16.h>
#include <stdint.h>

#define NROWS 8192
#define DIM 64
#define EPS 0.1f

typedef float f32x4 __attribute__((ext_vector_type(4)));
typedef short s16x8 __attribute__((ext_vector_type(8)));
typedef _Float16 h2 __attribute__((ext_vector_type(2)));

// ---------- helpers ----------

__device__ __forceinline__ float wave_reduce_add(float v) {
  #pragma unroll
  for (int off = 32; off > 0; off >>= 1) v += __shfl_down(v, off, 64);
  return v;
}

// pack two fp32 -> bf16x2 dword by truncation (1 v_perm); x -> low, y -> high.
__device__ __forceinline__ uint32_t pack_bf16_trunc(float x, float y) {
  return __builtin_amdgcn_perm(__float_as_uint(y), __float_as_uint(x), 0x07060302u);
}

// ---------- fp4 e2m1 encode/decode (block-scaled, scale applied manually) ----

#if __has_builtin(__builtin_amdgcn_cvt_scalef32_pk_f16_fp4)
#define CVT4H(kd, sel) __builtin_amdgcn_cvt_scalef32_pk_f16_fp4((kd), 1.0f, (sel))
#else
__device__ __forceinline__ h2 cvt4h_fb(uint32_t kd, int sel) {
  uint32_t byt  = (kd >> (sel * 8)) & 0xFFu;
  uint32_t selv = (byt & 0xFu) | ((byt >> 4) << 16);
  uint32_t tb = __builtin_amdgcn_perm(0x46444240u, 0x3E3C3800u, selv);
  uint32_t d  = ((tb & 0xFFu) << 8) | ((tb & 0xFF0000u) << 8);
  return __builtin_bit_cast(h2, d);
}
#define CVT4H(kd, sel) cvt4h_fb((kd), (sel))
#endif

#if __has_builtin(__builtin_amdgcn_cvt_scalef32_pk_fp4_f32)
__device__ __forceinline__ uint32_t enc4(float q0, float q1, float q2, float q3) {
  uint32_t pk = __builtin_amdgcn_cvt_scalef32_pk_fp4_f32(0u, q0, q1, 1.0f, 0);
  pk = __builtin_amdgcn_cvt_scalef32_pk_fp4_f32(pk, q2, q3, 1.0f, 1);
  return pk & 0xFFFFu;
}
#else
__device__ __forceinline__ uint32_t enc1(float q) {
  float c = fminf(floorf(2.f * q + 0.5f), 4.f);
  c += (q > 2.5f) ? 1.f : 0.f;
  c += (q > 3.5f) ? 1.f : 0.f;
  return (uint32_t)c;
}
__device__ __forceinline__ uint32_t enc4(float q0, float q1, float q2, float q3) {
  return enc1(q0) | (enc1(q1) << 4) | (enc1(q2) << 8) | (enc1(q3) << 12);
}
#endif

#define FP4DOT(kd, xv, acc)                                                          \
  acc = __builtin_amdgcn_fdot2(CVT4H((kd), 0), __builtin_bit_cast(h2, (xv).x), acc, false); \
  acc = __builtin_amdgcn_fdot2(CVT4H((kd), 1), __builtin_bit_cast(h2, (xv).y), acc, false); \
  acc = __builtin_amdgcn_fdot2(CVT4H((kd), 2), __builtin_bit_cast(h2, (xv).z), acc, false); \
  acc = __builtin_amdgcn_fdot2(CVT4H((kd), 3), __builtin_bit_cast(h2, (xv).w), acc, false);

#define FIN1(kd, xd_, sel)                                                           \
  {                                                                                  \
    h2 kvp = CVT4H((kd), sel);                                                       \
    h2 xp  = __builtin_bit_cast(h2, (xd_));                                          \
    s1b = __builtin_amdgcn_fdot2(kvp, xp, s1b, false);                               \
    float v0 = (float)kvp.x, v1 = (float)kvp.y;                                      \
    float x0 = (float)xp.x,  x1 = (float)xp.y;                                       \
    t2b = fmaf(v0 * x0, __logf(fmaxf(v0, 1e-8f)), t2b);                              \
    t2b = fmaf(v1 * x1, __logf(fmaxf(v1, 1e-8f)), t2b);                              \
  }
#define FINDOT(kd, xv) FIN1(kd, (xv).x, 0) FIN1(kd, (xv).y, 1) FIN1(kd, (xv).z, 2) FIN1(kd, (xv).w, 3)

// ---------- small kernels ----------

__global__ __launch_bounds__(256) void rownorm_kernel(
    const float* __restrict__ P, const float* __restrict__ Q,
    float* __restrict__ p2, float* __restrict__ q2,
    float* __restrict__ rowsum) {
  int wid  = threadIdx.x >> 6;
  int lane = threadIdx.x & 63;
  int row  = blockIdx.x * 4 + wid;  // 0..16383
  const float* X;
  float* out;
  int r;
  if (row < NROWS) { X = P; out = p2; r = row; }
  else             { X = Q; out = q2; r = row - NROWS; }
  float v = X[(size_t)r * DIM + lane];
  float s = wave_reduce_add(v * v);
  if (lane == 0) out[r] = s;
  if (row < NROWS && lane == 1) rowsum[r] = 0.f;   // zero for kgen's atomics
}

// vb16[i] = f16(64 / rowsum[i])  (pass m=0 fused into kgen's rowsum)
__global__ void v1_kernel(const float* __restrict__ rowsum,
                          unsigned short* __restrict__ vb16) {
  int i = blockIdx.x * blockDim.x + threadIdx.x;
  if (i < NROWS) vb16[i] = __half_as_ushort(__float2half(64.0f / rowsum[i]));
}

// ---------- kgen: MFMA bf16 -> fp4 K + e8m0 scales + row sums ----------
// LDS exactly 32 KB (A+B only) -> 5 blocks/CU (was 4 at 33.8 KB). p2/q2 read
// directly from global in the epilogue (64 KB, L2-hot, coalesced).

struct KgenSmem {
  unsigned char A[128 * 128];   // -2P tile, bf16, swizzled (16 KB)
  unsigned char B[128 * 128];   // Q tile, bf16, swizzled  (16 KB)
};

__device__ __forceinline__ int swiz_off(int row, int kc) {
  return row * 128 + ((kc ^ (row & 7)) << 4);
}

__global__ __launch_bounds__(256) void kgen_kernel(
    const float* __restrict__ P, const float* __restrict__ Q,
    const float* __restrict__ p2, const float* __restrict__ q2,
    unsigned char* __restrict__ K4, unsigned char* __restrict__ scales,
    float* __restrict__ rowsum) {
  __shared__ KgenSmem sm;
  const int t  = threadIdx.x;
  const int bi = blockIdx.y * 128;
  const int bj = blockIdx.x * 128;

  {
    const float4* P4 = (const float4*)(P + (size_t)bi * DIM);
    const float4* Q4 = (const float4*)(Q + (size_t)bj * DIM);
    #pragma unroll
    for (int it = 0; it < 4; ++it) {
      int idx = t + it * 256;
      int row = idx >> 3;
      int kc  = idx & 7;
      int g   = row * 16 + kc * 2;
      float4 a0 = P4[g], a1 = P4[g + 1];
      float4 b0 = Q4[g], b1 = Q4[g + 1];
      uint4 pa, pb;
      pa.x = pack_bf16_trunc(-2.f * a0.x, -2.f * a0.y);
      pa.y = pack_bf16_trunc(-2.f * a0.z, -2.f * a0.w);
      pa.z = pack_bf16_trunc(-2.f * a1.x, -2.f * a1.y);
      pa.w = pack_bf16_trunc(-2.f * a1.z, -2.f * a1.w);
      pb.x = pack_bf16_trunc(b0.x, b0.y);
      pb.y = pack_bf16_trunc(b0.z, b0.w);
      pb.z = pack_bf16_trunc(b1.x, b1.y);
      pb.w = pack_bf16_trunc(b1.z, b1.w);
      *(uint4*)(sm.A + swiz_off(row, kc)) = pa;
      *(uint4*)(sm.B + swiz_off(row, kc)) = pb;
    }
  }
  __syncthreads();

  const int w        = t >> 6;
  const int lane     = t & 63;
  const int quad     = lane >> 4;
  const int m16      = lane & 15;
  const int wave_row = (w >> 1) * 64;
  const int wave_col = (w & 1) * 64;

  // epilogue bias terms straight from global (L2-hot; coalesced 4/16 B loads)
  float pn[4];
  f32x4 qn[4];
  #pragma unroll
  for (int ti = 0; ti < 4; ++ti) pn[ti] = p2[bi + wave_row + ti * 16 + m16];
  #pragma unroll
  for (int tj = 0; tj < 4; ++tj)
    qn[tj] = *(const f32x4*)&q2[bj + wave_col + tj * 16 + quad * 4];

  f32x4 acc[4][4];
  #pragma unroll
  for (int ti = 0; ti < 4; ++ti)
    #pragma unroll
    for (int tj = 0; tj < 4; ++tj) acc[ti][tj] = qn[tj] + pn[ti];

  #pragma unroll
  for (int kstep = 0; kstep < 2; ++kstep) {
    const int kc = kstep * 4 + quad;
    s16x8 af[4], bf[4];
    #pragma unroll
    for (int ti = 0; ti < 4; ++ti)
      af[ti] = *(const s16x8*)(sm.A + swiz_off(wave_row + ti * 16 + m16, kc));
    #pragma unroll
    for (int tj = 0; tj < 4; ++tj)
      bf[tj] = *(const s16x8*)(sm.B + swiz_off(wave_col + tj * 16 + m16, kc));
    #pragma unroll
    for (int ti = 0; ti < 4; ++ti)
      #pragma unroll
      for (int tj = 0; tj < 4; ++tj)
        acc[ti][tj] = __builtin_amdgcn_mfma_f32_16x16x32_bf16(
            bf[tj], af[ti], acc[ti][tj], 0, 0, 0);   // swapped operands
  }

  // epilogue: k = exp(-10*sqrt(sq)); per-32col block max -> e8m0 scale;
  // e2m1 nibbles; ushort stores; fused rowsum.
  #pragma unroll
  for (int ti = 0; ti < 4; ++ti) {
    const int row = bi + wave_row + ti * 16 + m16;
    float kv[4][4];
    float mlo = 0.f, mhi = 0.f, rs = 0.f;
    #pragma unroll
    for (int tj = 0; tj < 4; ++tj) {
      f32x4 sq = acc[ti][tj];
      kv[tj][0] = __expf(-10.f * __builtin_amdgcn_sqrtf(fmaxf(sq.x, 0.f)));
      kv[tj][1] = __expf(-10.f * __builtin_amdgcn_sqrtf(fmaxf(sq.y, 0.f)));
      kv[tj][2] = __expf(-10.f * __builtin_amdgcn_sqrtf(fmaxf(sq.z, 0.f)));
      kv[tj][3] = __expf(-10.f * __builtin_amdgcn_sqrtf(fmaxf(sq.w, 0.f)));
      float mt = fmaxf(fmaxf(kv[tj][0], kv[tj][1]), fmaxf(kv[tj][2], kv[tj][3]));
      if (tj < 2) mlo = fmaxf(mlo, mt); else mhi = fmaxf(mhi, mt);
      rs += (kv[tj][0] + kv[tj][1]) + (kv[tj][2] + kv[tj][3]);
    }
    mlo = fmaxf(mlo, __shfl_xor(mlo, 16, 64));
    mlo = fmaxf(mlo, __shfl_xor(mlo, 32, 64));
    mhi = fmaxf(mhi, __shfl_xor(mhi, 16, 64));
    mhi = fmaxf(mhi, __shfl_xor(mhi, 32, 64));
    uint32_t eblo = (__float_as_uint(mlo) >> 23) - 1u;
    uint32_t ebhi = (__float_as_uint(mhi) >> 23) - 1u;
    float silo = __uint_as_float((254u - eblo) << 23);
    float sihi = __uint_as_float((254u - ebhi) << 23);
    #pragma unroll
    for (int tj = 0; tj < 4; ++tj) {
      float si = (tj < 2) ? silo : sihi;
      uint32_t pk = enc4(kv[tj][0] * si, kv[tj][1] * si,
                         kv[tj][2] * si, kv[tj][3] * si);
      *(unsigned short*)(K4 + (size_t)row * (NROWS / 2) +
                         ((bj + wave_col + tj * 16 + quad * 4) >> 1)) =
          (unsigned short)pk;
    }
    if (quad == 0) {
      *(unsigned short*)(scales + (size_t)row * 256 + ((bj + wave_col) >> 5)) =
          (unsigned short)((eblo & 0xFFu) | ((ebhi & 0xFFu) << 8));
    }
    float v = rs;
    v += __shfl_xor(v, 16, 64);
    v += __shfl_xor(v, 32, 64);
    if (quad == 0) atomicAdd(&rowsum[row], v);
  }
}

// ---------- matvec_fp4 (r12-proven): 2048 blocks, 1 row/wave ----------

__global__ __launch_bounds__(256) void matvec_fp4(
    const unsigned char* __restrict__ K4, const unsigned char* __restrict__ scales,
    const unsigned short* __restrict__ xin, unsigned short* __restrict__ yout) {
  const int t = threadIdx.x, lane = t & 63, w = t >> 6;
  const int row = blockIdx.x * 4 + w;
  const uint4* krow = (const uint4*)(K4 + (size_t)row * (NROWS / 2));
  const unsigned char* srow = scales + (size_t)row * 256;
  const uint4* x4 = (const uint4*)xin;   // 8192 f16 = 1024 uint4
  float total = 0.f;
  #pragma unroll
  for (int s = 0; s < 4; ++s) {
    const int b = s * 64 + lane;           // 32-elem block index
    uint4 kq = krow[b];
    float S = __uint_as_float((uint32_t)srow[b] << 23);
    uint4 xa = x4[b * 4 + 0], xb = x4[b * 4 + 1];
    uint4 xc = x4[b * 4 + 2], xd = x4[b * 4 + 3];
    float a0 = 0.f, a1 = 0.f;
    FP4DOT(kq.x, xa, a0)
    FP4DOT(kq.y, xb, a1)
    FP4DOT(kq.z, xc, a0)
    FP4DOT(kq.w, xd, a1)
    total = fmaf(S, a0 + a1, total);
  }
  float sm = wave_reduce_add(total);
  if (lane == 0) yout[row] = __half_as_ushort(__float2half(1.0f / sm));
}

// ---------- final_fp4 (r12-proven): fused 10th matvec + loss ----------

__global__ __launch_bounds__(256) void final_fp4(
    const unsigned char* __restrict__ K4, const unsigned char* __restrict__ scales,
    const unsigned short* __restrict__ xin, float* __restrict__ partials) {
  const int t = threadIdx.x, lane = t & 63, w = t >> 6;
  const int row = blockIdx.x * 4 + w;
  const uint4* krow = (const uint4*)(K4 + (size_t)row * (NROWS / 2));
  const unsigned char* srow = scales + (size_t)row * 256;
  const uint4* x4 = (const uint4*)xin;
  float s1 = 0.f, s2 = 0.f;
  #pragma unroll
  for (int s = 0; s < 4; ++s) {
    const int b = s * 64 + lane;
    uint4 kq = krow[b];
    uint32_t sb = srow[b];
    float S = __uint_as_float(sb << 23);
    float lnS = ((float)(int)sb - 127.f) * 0.69314718f;
    uint4 xa = x4[b * 4 + 0], xb = x4[b * 4 + 1];
    uint4 xc = x4[b * 4 + 2], xd = x4[b * 4 + 3];
    float s1b = 0.f, t2b = 0.f;
    FINDOT(kq.x, xa)
    FINDOT(kq.y, xb)
    FINDOT(kq.z, xc)
    FINDOT(kq.w, xd)
    s1 = fmaf(S, s1b, s1);
    s2 = fmaf(S, fmaf(lnS, s1b, t2b), s2);
  }
  s1 = wave_reduce_add(s1);
  s2 = wave_reduce_add(s2);
  __shared__ float sred[4];
  if (lane == 0) sred[w] = (-EPS) * s2 / s1;
  __syncthreads();
  if (t == 0) partials[blockIdx.x] = sred[0] + sred[1] + sred[2] + sred[3];
}

// Sum 2048 partials -> out[0].
__global__ __launch_bounds__(256) void reduce_kernel(
    const float* __restrict__ partials, float* __restrict__ out) {
  const int t = threadIdx.x;
  float s = 0.f;
  #pragma unroll
  for (int i = 0; i < 8; ++i) s += partials[t + i * 256];
  s = wave_reduce_add(s);
  __shared__ float red[4];
  int lane = t & 63, wid = t >> 6;
  if (lane == 0) red[wid] = s;
  __syncthreads();
  if (t == 0) out[0] = red[0] + red[1] + red[2] + red[3];
}

// ---------- launch ----------

extern "C" void kernel_launch(void* const* d_in, const int* in_sizes, int n_in,
                              void* d_out, int out_size, void* d_ws, size_t ws_size,
                              hipStream_t stream) {
  const float* P = (const float*)d_in[0];
  const float* Q = (const float*)d_in[1];
  float* out = (float*)d_out;

  char* ws = (char*)d_ws;
  unsigned char* K4     = (unsigned char*)ws;                    // 33554432 B
  unsigned char* scales = (unsigned char*)(ws + 33554432);       // 2097152 B
  float* p2       = (float*)(ws + 35651584);
  float* q2       = p2 + NROWS;
  float* rowsum   = q2 + NROWS;
  float* partials = rowsum + NROWS;                              // 2048 (slot 8192)
  unsigned short* ub16 = (unsigned short*)(partials + NROWS);
  unsigned short* vb16 = ub16 + NROWS;

  rownorm_kernel<<<(2 * NROWS) / 4, 256, 0, stream>>>(P, Q, p2, q2, rowsum);
  kgen_kernel<<<dim3(NROWS / 128, NROWS / 128), 256, 0, stream>>>(
      P, Q, p2, q2, K4, scales, rowsum);
  v1_kernel<<<NROWS / 256, 256, 0, stream>>>(rowsum, vb16);

  // Passes m=1..8 (m=0 fused into kgen rowsum): after m=8, vb16 holds v5.
  for (int m = 1; m < 9; ++m) {
    const unsigned short* xin = (m & 1) ? vb16 : ub16;
    unsigned short* yout      = (m & 1) ? ub16 : vb16;
    matvec_fp4<<<NROWS / 4, 256, 0, stream>>>(K4, scales, xin, yout);
  }

  final_fp4<<<NROWS / 4, 256, 0, stream>>>(K4, scales, vb16, partials);
  reduce_kernel<<<1, 256, 0, stream>>>(partials, out);
}

// Round 15
// 218.657 us; speedup vs baseline: 5.3399x; 1.0612x over previous
//
#include <hip/hip_runtime.h>
#include <hip/hip_fp16.h>
#include <stdint.h>

#define NROWS 8192
#define DIM 64
#define EPS 0.1f

typedef float f32x4 __attribute__((ext_vector_type(4)));
typedef short s16x8 __attribute__((ext_vector_type(8)));
typedef _Float16 h2 __attribute__((ext_vector_type(2)));

// ---------- helpers ----------

__device__ __forceinline__ float wave_reduce_add(float v) {
  #pragma unroll
  for (int off = 32; off > 0; off >>= 1) v += __shfl_down(v, off, 64);
  return v;
}

// pack two fp32 -> bf16x2 dword by truncation (1 v_perm); x -> low, y -> high.
__device__ __forceinline__ uint32_t pack_bf16_trunc(float x, float y) {
  return __builtin_amdgcn_perm(__float_as_uint(y), __float_as_uint(x), 0x07060302u);
}

// Column permutation: K4 stores columns in pi-order so kgen's per-lane nibbles
// are contiguous. pi shuffles only bits 0..5 (within a 64-col half-tile):
// orig c = tj*16 + quad*4 + e  ->  pi(c) = quad*16 + tj*4 + e.
// x vectors live in pi-order; y (and v1) store at pi(i); sums are order-invariant.
__device__ __forceinline__ int pi_idx(int i) {
  int r = i & 63;
  int tj = r >> 4, quad = (r >> 2) & 3, e = r & 3;
  return (i & ~63) | (quad * 16 + tj * 4 + e);
}

// ---------- fp4 e2m1 encode/decode (block-scaled, scale applied manually) ----

#if __has_builtin(__builtin_amdgcn_cvt_scalef32_pk_f16_fp4)
#define CVT4H(kd, sel) __builtin_amdgcn_cvt_scalef32_pk_f16_fp4((kd), 1.0f, (sel))
#else
__device__ __forceinline__ h2 cvt4h_fb(uint32_t kd, int sel) {
  uint32_t byt  = (kd >> (sel * 8)) & 0xFFu;
  uint32_t selv = (byt & 0xFu) | ((byt >> 4) << 16);
  uint32_t tb = __builtin_amdgcn_perm(0x46444240u, 0x3E3C3800u, selv);
  uint32_t d  = ((tb & 0xFFu) << 8) | ((tb & 0xFF0000u) << 8);
  return __builtin_bit_cast(h2, d);
}
#define CVT4H(kd, sel) cvt4h_fb((kd), (sel))
#endif

#if __has_builtin(__builtin_amdgcn_cvt_scalef32_pk_fp4_f32)
__device__ __forceinline__ uint32_t enc4(float q0, float q1, float q2, float q3) {
  uint32_t pk = __builtin_amdgcn_cvt_scalef32_pk_fp4_f32(0u, q0, q1, 1.0f, 0);
  pk = __builtin_amdgcn_cvt_scalef32_pk_fp4_f32(pk, q2, q3, 1.0f, 1);
  return pk & 0xFFFFu;
}
#else
__device__ __forceinline__ uint32_t enc1(float q) {
  float c = fminf(floorf(2.f * q + 0.5f), 4.f);
  c += (q > 2.5f) ? 1.f : 0.f;
  c += (q > 3.5f) ? 1.f : 0.f;
  return (uint32_t)c;
}
__device__ __forceinline__ uint32_t enc4(float q0, float q1, float q2, float q3) {
  return enc1(q0) | (enc1(q1) << 4) | (enc1(q2) << 8) | (enc1(q3) << 12);
}
#endif

#define FP4DOT(kd, xv, acc)                                                          \
  acc = __builtin_amdgcn_fdot2(CVT4H((kd), 0), __builtin_bit_cast(h2, (xv).x), acc, false); \
  acc = __builtin_amdgcn_fdot2(CVT4H((kd), 1), __builtin_bit_cast(h2, (xv).y), acc, false); \
  acc = __builtin_amdgcn_fdot2(CVT4H((kd), 2), __builtin_bit_cast(h2, (xv).z), acc, false); \
  acc = __builtin_amdgcn_fdot2(CVT4H((kd), 3), __builtin_bit_cast(h2, (xv).w), acc, false);

#define FIN1(kd, xd_, sel)                                                           \
  {                                                                                  \
    h2 kvp = CVT4H((kd), sel);                                                       \
    h2 xp  = __builtin_bit_cast(h2, (xd_));                                          \
    s1b = __builtin_amdgcn_fdot2(kvp, xp, s1b, false);                               \
    float v0 = (float)kvp.x, v1 = (float)kvp.y;                                      \
    float x0 = (float)xp.x,  x1 = (float)xp.y;                                       \
    t2b = fmaf(v0 * x0, __logf(fmaxf(v0, 1e-8f)), t2b);                              \
    t2b = fmaf(v1 * x1, __logf(fmaxf(v1, 1e-8f)), t2b);                              \
  }
#define FINDOT(kd, xv) FIN1(kd, (xv).x, 0) FIN1(kd, (xv).y, 1) FIN1(kd, (xv).z, 2) FIN1(kd, (xv).w, 3)

// ---------- small kernels ----------

__global__ __launch_bounds__(256) void rownorm_kernel(
    const float* __restrict__ P, const float* __restrict__ Q,
    float* __restrict__ p2, float* __restrict__ q2,
    float* __restrict__ rowsum) {
  int wid  = threadIdx.x >> 6;
  int lane = threadIdx.x & 63;
  int row  = blockIdx.x * 4 + wid;  // 0..16383
  const float* X;
  float* out;
  int r;
  if (row < NROWS) { X = P; out = p2; r = row; }
  else             { X = Q; out = q2; r = row - NROWS; }
  float v = X[(size_t)r * DIM + lane];
  float s = wave_reduce_add(v * v);
  if (lane == 0) out[r] = s;
  if (row < NROWS && lane == 1) rowsum[r] = 0.f;   // zero for kgen's atomics
}

// vb16[pi(i)] = f16(64 / rowsum[i])  (pass m=0 fused into kgen's rowsum)
__global__ void v1_kernel(const float* __restrict__ rowsum,
                          unsigned short* __restrict__ vb16) {
  int i = blockIdx.x * blockDim.x + threadIdx.x;
  if (i < NROWS) vb16[pi_idx(i)] = __half_as_ushort(__float2half(64.0f / rowsum[i]));
}

// ---------- kgen: MFMA bf16 -> fp4 K (pi-ordered cols) + e8m0 scales + rowsum ----
// 32 KB LDS (A+B). Stores: one dwordx2 of 16 contiguous nibbles per lane per ti
// (pi column order makes the lane's 4 tj-words adjacent) — no scattered ushorts.

struct KgenSmem {
  unsigned char A[128 * 128];   // -2P tile, bf16, swizzled (16 KB)
  unsigned char B[128 * 128];   // Q tile, bf16, swizzled  (16 KB)
};

__device__ __forceinline__ int swiz_off(int row, int kc) {
  return row * 128 + ((kc ^ (row & 7)) << 4);
}

__global__ __launch_bounds__(256) void kgen_kernel(
    const float* __restrict__ P, const float* __restrict__ Q,
    const float* __restrict__ p2, const float* __restrict__ q2,
    unsigned char* __restrict__ K4, unsigned char* __restrict__ scales,
    float* __restrict__ rowsum) {
  __shared__ KgenSmem sm;
  const int t  = threadIdx.x;
  const int bi = blockIdx.y * 128;
  const int bj = blockIdx.x * 128;

  {
    const float4* P4 = (const float4*)(P + (size_t)bi * DIM);
    const float4* Q4 = (const float4*)(Q + (size_t)bj * DIM);
    #pragma unroll
    for (int it = 0; it < 4; ++it) {
      int idx = t + it * 256;
      int row = idx >> 3;
      int kc  = idx & 7;
      int g   = row * 16 + kc * 2;
      float4 a0 = P4[g], a1 = P4[g + 1];
      float4 b0 = Q4[g], b1 = Q4[g + 1];
      uint4 pa, pb;
      pa.x = pack_bf16_trunc(-2.f * a0.x, -2.f * a0.y);
      pa.y = pack_bf16_trunc(-2.f * a0.z, -2.f * a0.w);
      pa.z = pack_bf16_trunc(-2.f * a1.x, -2.f * a1.y);
      pa.w = pack_bf16_trunc(-2.f * a1.z, -2.f * a1.w);
      pb.x = pack_bf16_trunc(b0.x, b0.y);
      pb.y = pack_bf16_trunc(b0.z, b0.w);
      pb.z = pack_bf16_trunc(b1.x, b1.y);
      pb.w = pack_bf16_trunc(b1.z, b1.w);
      *(uint4*)(sm.A + swiz_off(row, kc)) = pa;
      *(uint4*)(sm.B + swiz_off(row, kc)) = pb;
    }
  }
  __syncthreads();

  const int w        = t >> 6;
  const int lane     = t & 63;
  const int quad     = lane >> 4;
  const int m16      = lane & 15;
  const int wave_row = (w >> 1) * 64;
  const int wave_col = (w & 1) * 64;

  float pn[4];
  f32x4 qn[4];
  #pragma unroll
  for (int ti = 0; ti < 4; ++ti) pn[ti] = p2[bi + wave_row + ti * 16 + m16];
  #pragma unroll
  for (int tj = 0; tj < 4; ++tj)
    qn[tj] = *(const f32x4*)&q2[bj + wave_col + tj * 16 + quad * 4];

  f32x4 acc[4][4];
  #pragma unroll
  for (int ti = 0; ti < 4; ++ti)
    #pragma unroll
    for (int tj = 0; tj < 4; ++tj) acc[ti][tj] = qn[tj] + pn[ti];

  #pragma unroll
  for (int kstep = 0; kstep < 2; ++kstep) {
    const int kc = kstep * 4 + quad;
    s16x8 af[4], bf[4];
    #pragma unroll
    for (int ti = 0; ti < 4; ++ti)
      af[ti] = *(const s16x8*)(sm.A + swiz_off(wave_row + ti * 16 + m16, kc));
    #pragma unroll
    for (int tj = 0; tj < 4; ++tj)
      bf[tj] = *(const s16x8*)(sm.B + swiz_off(wave_col + tj * 16 + m16, kc));
    #pragma unroll
    for (int ti = 0; ti < 4; ++ti)
      #pragma unroll
      for (int tj = 0; tj < 4; ++tj)
        acc[ti][tj] = __builtin_amdgcn_mfma_f32_16x16x32_bf16(
            bf[tj], af[ti], acc[ti][tj], 0, 0, 0);   // swapped operands
  }

  // epilogue: k = exp(-10*sqrt(sq)); block = 32 pi-cols = quad-pair;
  // pair max -> e8m0 scale; e2m1 nibbles; ONE dwordx2 store per ti.
  #pragma unroll
  for (int ti = 0; ti < 4; ++ti) {
    const int row = bi + wave_row + ti * 16 + m16;
    float kv[4][4];
    float mx = 0.f, rs = 0.f;
    #pragma unroll
    for (int tj = 0; tj < 4; ++tj) {
      f32x4 sq = acc[ti][tj];
      kv[tj][0] = __expf(-10.f * __builtin_amdgcn_sqrtf(fmaxf(sq.x, 0.f)));
      kv[tj][1] = __expf(-10.f * __builtin_amdgcn_sqrtf(fmaxf(sq.y, 0.f)));
      kv[tj][2] = __expf(-10.f * __builtin_amdgcn_sqrtf(fmaxf(sq.z, 0.f)));
      kv[tj][3] = __expf(-10.f * __builtin_amdgcn_sqrtf(fmaxf(sq.w, 0.f)));
      float mt = fmaxf(fmaxf(kv[tj][0], kv[tj][1]), fmaxf(kv[tj][2], kv[tj][3]));
      mx = fmaxf(mx, mt);
      rs += (kv[tj][0] + kv[tj][1]) + (kv[tj][2] + kv[tj][3]);
    }
    // block max over the quad-pair (quads {0,1} share a 32-col pi-block; {2,3} too)
    mx = fmaxf(mx, __shfl_xor(mx, 16, 64));
    uint32_t eb = (__float_as_uint(mx) >> 23) - 1u;
    float si = __uint_as_float((254u - eb) << 23);   // 1/S, S = 2^(e-1)
    uint32_t pk0 = enc4(kv[0][0] * si, kv[0][1] * si, kv[0][2] * si, kv[0][3] * si);
    uint32_t pk1 = enc4(kv[1][0] * si, kv[1][1] * si, kv[1][2] * si, kv[1][3] * si);
    uint32_t pk2 = enc4(kv[2][0] * si, kv[2][1] * si, kv[2][2] * si, kv[2][3] * si);
    uint32_t pk3 = enc4(kv[3][0] * si, kv[3][1] * si, kv[3][2] * si, kv[3][3] * si);
    // lane's 16 nibbles are pi-cols [wave_col + quad*16, +16) -> 8 contiguous bytes
    uint2 st = uint2{pk0 | (pk1 << 16), pk2 | (pk3 << 16)};
    *(uint2*)(K4 + (size_t)row * (NROWS / 2) + ((bj + wave_col) >> 1) + quad * 8) = st;
    // scale bytes: pair0 (quads 0,1) and pair1 (quads 2,3); quad0 stores both
    uint32_t eb2 = (uint32_t)__shfl_xor((int)eb, 32, 64);  // quad0 <- quad2
    if (quad == 0) {
      *(unsigned short*)(scales + (size_t)row * 256 + ((bj + wave_col) >> 5)) =
          (unsigned short)((eb & 0xFFu) | ((eb2 & 0xFFu) << 8));
    }
    float v = rs;
    v += __shfl_xor(v, 16, 64);
    v += __shfl_xor(v, 32, 64);
    if (quad == 0) atomicAdd(&rowsum[row], v);
  }
}

// ---------- matvec_fp4: 2048 blocks, 1 row/wave; y stored at pi(row) ----------

__global__ __launch_bounds__(256) void matvec_fp4(
    const unsigned char* __restrict__ K4, const unsigned char* __restrict__ scales,
    const unsigned short* __restrict__ xin, unsigned short* __restrict__ yout) {
  const int t = threadIdx.x, lane = t & 63, w = t >> 6;
  const int row = blockIdx.x * 4 + w;
  const uint4* krow = (const uint4*)(K4 + (size_t)row * (NROWS / 2));
  const unsigned char* srow = scales + (size_t)row * 256;
  const uint4* x4 = (const uint4*)xin;   // 8192 f16 = 1024 uint4 (pi-order)
  float total = 0.f;
  #pragma unroll
  for (int s = 0; s < 4; ++s) {
    const int b = s * 64 + lane;           // 32-elem pi-block index
    uint4 kq = krow[b];
    float S = __uint_as_float((uint32_t)srow[b] << 23);
    uint4 xa = x4[b * 4 + 0], xb = x4[b * 4 + 1];
    uint4 xc = x4[b * 4 + 2], xd = x4[b * 4 + 3];
    float a0 = 0.f, a1 = 0.f;
    FP4DOT(kq.x, xa, a0)
    FP4DOT(kq.y, xb, a1)
    FP4DOT(kq.z, xc, a0)
    FP4DOT(kq.w, xd, a1)
    total = fmaf(S, a0 + a1, total);
  }
  float sm = wave_reduce_add(total);
  if (lane == 0) yout[pi_idx(row)] = __half_as_ushort(__float2half(1.0f / sm));
}

// ---------- final_fp4: fused 10th matvec + loss ----------

__global__ __launch_bounds__(256) void final_fp4(
    const unsigned char* __restrict__ K4, const unsigned char* __restrict__ scales,
    const unsigned short* __restrict__ xin, float* __restrict__ partials) {
  const int t = threadIdx.x, lane = t & 63, w = t >> 6;
  const int row = blockIdx.x * 4 + w;
  const uint4* krow = (const uint4*)(K4 + (size_t)row * (NROWS / 2));
  const unsigned char* srow = scales + (size_t)row * 256;
  const uint4* x4 = (const uint4*)xin;
  float s1 = 0.f, s2 = 0.f;
  #pragma unroll
  for (int s = 0; s < 4; ++s) {
    const int b = s * 64 + lane;
    uint4 kq = krow[b];
    uint32_t sb = srow[b];
    float S = __uint_as_float(sb << 23);
    float lnS = ((float)(int)sb - 127.f) * 0.69314718f;
    uint4 xa = x4[b * 4 + 0], xb = x4[b * 4 + 1];
    uint4 xc = x4[b * 4 + 2], xd = x4[b * 4 + 3];
    float s1b = 0.f, t2b = 0.f;
    FINDOT(kq.x, xa)
    FINDOT(kq.y, xb)
    FINDOT(kq.z, xc)
    FINDOT(kq.w, xd)
    s1 = fmaf(S, s1b, s1);
    s2 = fmaf(S, fmaf(lnS, s1b, t2b), s2);
  }
  s1 = wave_reduce_add(s1);
  s2 = wave_reduce_add(s2);
  __shared__ float sred[4];
  if (lane == 0) sred[w] = (-EPS) * s2 / s1;
  __syncthreads();
  if (t == 0) partials[blockIdx.x] = sred[0] + sred[1] + sred[2] + sred[3];
}

// Sum 2048 partials -> out[0].
__global__ __launch_bounds__(256) void reduce_kernel(
    const float* __restrict__ partials, float* __restrict__ out) {
  const int t = threadIdx.x;
  float s = 0.f;
  #pragma unroll
  for (int i = 0; i < 8; ++i) s += partials[t + i * 256];
  s = wave_reduce_add(s);
  __shared__ float red[4];
  int lane = t & 63, wid = t >> 6;
  if (lane == 0) red[wid] = s;
  __syncthreads();
  if (t == 0) out[0] = red[0] + red[1] + red[2] + red[3];
}

// ---------- launch ----------

extern "C" void kernel_launch(void* const* d_in, const int* in_sizes, int n_in,
                              void* d_out, int out_size, void* d_ws, size_t ws_size,
                              hipStream_t stream) {
  const float* P = (const float*)d_in[0];
  const float* Q = (const float*)d_in[1];
  float* out = (float*)d_out;

  char* ws = (char*)d_ws;
  unsigned char* K4     = (unsigned char*)ws;                    // 33554432 B
  unsigned char* scales = (unsigned char*)(ws + 33554432);       // 2097152 B
  float* p2       = (float*)(ws + 35651584);
  float* q2       = p2 + NROWS;
  float* rowsum   = q2 + NROWS;
  float* partials = rowsum + NROWS;                              // 2048 (slot 8192)
  unsigned short* ub16 = (unsigned short*)(partials + NROWS);
  unsigned short* vb16 = ub16 + NROWS;

  rownorm_kernel<<<(2 * NROWS) / 4, 256, 0, stream>>>(P, Q, p2, q2, rowsum);
  kgen_kernel<<<dim3(NROWS / 128, NROWS / 128), 256, 0, stream>>>(
      P, Q, p2, q2, K4, scales, rowsum);
  v1_kernel<<<NROWS / 256, 256, 0, stream>>>(rowsum, vb16);

  // Passes m=1..8 (m=0 fused into kgen rowsum): after m=8, vb16 holds v5.
  for (int m = 1; m < 9; ++m) {
    const unsigned short* xin = (m & 1) ? vb16 : ub16;
    unsigned short* yout      = (m & 1) ? ub16 : vb16;
    matvec_fp4<<<NROWS / 4, 256, 0, stream>>>(K4, scales, xin, yout);
  }

  final_fp4<<<NROWS / 4, 256, 0, stream>>>(K4, scales, vb16, partials);
  reduce_kernel<<<1, 256, 0, stream>>>(partials, out);
}